// Round 14
// baseline (132.693 us; speedup 1.0000x reference)
//
#include <hip/hip_runtime.h>
#include <hip/hip_fp16.h>
#include <hip/hip_bf16.h>

// B=64, M=16, T=2048, L=64, K=32, N=1985
#define B_ 64
#define M_ 16
#define T_ 2048
#define L_ 64
#define K_ 32
#define N_ (T_ - L_ + 1)   // 1985
#define NQP 512            // padded n-quad rows per m (no guards on pen loads)
#define TN 64              // n-positions per block
#define NBB 4              // batches per block, processed SEQUENTIALLY (pen in regs)
#define NTH 256            // 4 waves: wave w owns n-subtile [16w,16w+16), both k-tiles
#define XROW 144           // per-plane row elems; j<=123 needed. 72 dw == 8 (mod 32)
                           // -> planes at bank offs {0,8,16,24}: uniform 4/bank (floor).
#define STSTR 72           // st row stride elems (16B-aligned b128 reads)
#define SQSTR 64           // sqw row stride (reads are q-only broadcasts)

typedef __attribute__((ext_vector_type(8))) short bf16x8;
typedef __attribute__((ext_vector_type(4))) float f32x4;

__device__ __forceinline__ unsigned short f2bf(float f) {
    __hip_bfloat16 h = __float2bfloat16(f);
    return __builtin_bit_cast(unsigned short, h);
}
__device__ __forceinline__ float h2f(unsigned short u) {
    return __half2float(__builtin_bit_cast(__half, u));
}

// pen_h[m][nq][k][r] = fp16( elu(-pmap[k][m][clamp(4*nq+r)]) + 2 )
// A quad's 16 lanes (k) read 128B contiguous. ss[k] = sum_l s^2. out[] = +inf.
__global__ void pen_init_kernel(const float* __restrict__ pmap,
                                const float* __restrict__ shp,
                                unsigned short* __restrict__ pen_h,
                                float* __restrict__ ss_ws,
                                unsigned* __restrict__ out) {
    const int gid = blockIdx.x * 256 + threadIdx.x;   // 0 .. M_*NQP*K_-1 (262144)
    if (gid < B_ * K_) out[gid] = 0x7F800000u;  // +inf
    if (gid < K_) {
        float s = 0.f;
        for (int l = 0; l < L_; ++l) { float v = shp[gid * L_ + l]; s = fmaf(v, v, s); }
        ss_ws[gid] = s;
    }
    if (gid < M_ * NQP * K_) {
        const int m  = gid >> 14;            // / (NQP*K_)
        const int rem = gid & 16383;
        const int nq = rem >> 5;             // / K_
        const int k  = rem & 31;
        const float* src = pmap + ((size_t)k * M_ + m) * N_;
        ushort4 o;
        unsigned short* po = (unsigned short*)&o;
#pragma unroll
        for (int i = 0; i < 4; ++i) {
            int n = 4 * nq + i; if (n >= N_) n = N_ - 1;   // clamp: masked at min
            const float p = src[n];
            const float pe = (p < 0.f) ? (2.f - p) : (__expf(-p) + 1.f);
            po[i] = __builtin_bit_cast(unsigned short, __float2half(pe));
        }
        *(ushort4*)(pen_h + (size_t)gid * 4) = o;
    }
}

__global__ __launch_bounds__(NTH, 2)
void shapelet_mfma_kernel(const float* __restrict__ x,
                          const float* __restrict__ shp,
                          const unsigned short* __restrict__ pen_h,
                          const float* __restrict__ ss_ws,
                          unsigned* __restrict__ out) {
    // LDS: 18432 + 4608 + 4096 = 27136 B; x/sqw restaged per b inside the block.
    __shared__ __align__(16) unsigned short xbuf4[M_][4][XROW];
    __shared__ __align__(16) unsigned short st[K_][STSTR];   // shapelets bf16
    __shared__ __align__(16) float sqw[M_][SQSTR];           // fp32 sliding sum x^2

    const int tid = threadIdx.x;
    const int n0 = blockIdx.x * TN;
    const int b0 = blockIdx.y * NBB;
    const bool fast = (n0 + 128 <= T_);   // false only for last tile (n0=1984)

    // ---- per-lane MFMA coordinates ----
    const int lane = tid & 63;
    const int w  = tid >> 6;       // wave -> n-subtile [16w, 16w+16)
    const int rl = lane & 15;      // A-row (n within subtile) / B-col (k within tile)
    const int q  = lane >> 4;      // quad
    const int sp = rl & 3;                          // shift plane
    const int e0 = 16 * w + 8 * q + (rl & ~3);      // 4-aligned elem base (max 84)
    const int eq = e0 >> 2;                         // uint2 index (max 21; +9 <= 30 < 36)
    const int nrow = n0 + 16 * w + 4 * q;           // lane's 4 output rows: nrow + reg

    // ---- pen for the WHOLE block in registers: 16 m x 2 k-halves x 4 fp16 ----
    // pen_h[m][nq][k][r]: lane base at (nq_l, k=rl); m-step = NQP*K*4 halves.
    const int nq_l = (n0 >> 2) + 4 * w + q;
    const unsigned short* pb = pen_h + (((size_t)nq_l) * K_ + rl) * 4;
    ushort4 penr0[M_], penr1[M_];
#pragma unroll
    for (int m = 0; m < M_; ++m) {
        penr0[m] = *(const ushort4*)(pb + (size_t)m * (NQP * K_ * 4));
        penr1[m] = *(const ushort4*)(pb + (size_t)m * (NQP * K_ * 4) + 64);
    }
    const float ssk0 = ss_ws[rl], ssk1 = ss_ws[16 + rl];

    // ---- stage shapelets st[k][l] bf16 (b-invariant, once) ----
    for (int i = tid; i < K_ * 16; i += NTH) {
        const int k = i >> 4, l4 = (i & 15) * 4;
        float4 v = *(const float4*)(shp + k * L_ + l4);
        ushort4 sv = { f2bf(v.x), f2bf(v.y), f2bf(v.z), f2bf(v.w) };
        *(ushort4*)&st[k][l4] = sv;
    }

    bf16x8 bfr[2][2];
    const f32x4 zero = (f32x4)0.f;

#pragma unroll 1
    for (int bi = 0; bi < NBB; ++bi) {
        const int b = b0 + bi;

        // ---- stage x as 4 shifted bf16 planes: j4 = 0..120 (j cover 0..123) ----
        const float* xb = x + ((size_t)b * M_) * T_ + n0;
        for (int g = tid; g < M_ * 31; g += NTH) {
            const int m = g / 31, j4 = (g - m * 31) * 4;
            const float* src = xb + m * T_ + j4;
            float h[8];
            if (fast) {
                float4 v0 = *(const float4*)src;
                float4 v1 = *(const float4*)(src + 4);
                h[0] = v0.x; h[1] = v0.y; h[2] = v0.z; h[3] = v0.w;
                h[4] = v1.x; h[5] = v1.y; h[6] = v1.z; h[7] = v1.w;
            } else {
#pragma unroll
                for (int i = 0; i < 8; ++i)
                    h[i] = (n0 + j4 + i < T_) ? src[i] : 0.f;
            }
            unsigned short hb[8];
#pragma unroll
            for (int i = 0; i < 8; ++i) hb[i] = f2bf(h[i]);
#pragma unroll
            for (int s = 0; s < 4; ++s) {
                ushort4 sv = { hb[s], hb[s + 1], hb[s + 2], hb[s + 3] };
                *(ushort4*)&xbuf4[m][s][j4] = sv;
            }
        }
        // ---- sqw fp32 sliding window: threads 0..127 -> (m, 8-n chunk) ----
        if (tid < M_ * 8) {
            const int m = tid >> 3, j0 = (tid & 7) * 8;
            const float* xr = x + ((size_t)b * M_ + m) * T_ + n0;
            float s = 0.f;
            if (fast) {
#pragma unroll
                for (int qd = 0; qd < 16; ++qd) {
                    float4 v = *(const float4*)(xr + j0 + qd * 4);
                    s = fmaf(v.x, v.x, s); s = fmaf(v.y, v.y, s);
                    s = fmaf(v.z, v.z, s); s = fmaf(v.w, v.w, s);
                }
                sqw[m][j0] = s;
#pragma unroll
                for (int d = 1; d < 8; ++d) {
                    float a = xr[j0 + d + L_ - 1], r = xr[j0 + d - 1];
                    s += a * a - r * r;
                    sqw[m][j0 + d] = s;
                }
            } else {
                for (int l = 0; l < L_; ++l) {
                    float v = (n0 + j0 + l < T_) ? xr[j0 + l] : 0.f;
                    s = fmaf(v, v, s);
                }
                sqw[m][j0] = s;
                for (int d = 1; d < 8; ++d) {
                    float a = (n0 + j0 + d + L_ - 1 < T_) ? xr[j0 + d + L_ - 1] : 0.f;
                    float r = (n0 + j0 + d - 1 < T_) ? xr[j0 + d - 1] : 0.f;
                    s += a * a - r * r;
                    sqw[m][j0 + d] = s;
                }
            }
        }
        __syncthreads();

        if (bi == 0) {
            // b_frags from st (written before first barrier): st[16t+rl][8q+32h..+7]
#pragma unroll
            for (int t = 0; t < 2; ++t)
#pragma unroll
                for (int h = 0; h < 2; ++h)
                    bfr[t][h] = *(const bf16x8*)&st[16 * t + rl][8 * q + 32 * h];
        }

        // ---- m-loop: PURE LDS + MFMA + VALU (zero global instructions) ----
        f32x4 wd0 = (f32x4)0.f, wd1 = (f32x4)0.f;
#pragma unroll
        for (int m = 0; m < M_; ++m) {
            const uint2* prow = (const uint2*)&xbuf4[m][sp][0];
            uint2 lo0 = prow[eq],     hi0 = prow[eq + 1];        // frag h=0
            uint2 lo1 = prow[eq + 8], hi1 = prow[eq + 9];        // frag h=1 (+32)
            union { uint2 u2[2]; bf16x8 v; } fa0, fa1;
            fa0.u2[0] = lo0; fa0.u2[1] = hi0;
            fa1.u2[0] = lo1; fa1.u2[1] = hi1;

            f32x4 c0_ = __builtin_amdgcn_mfma_f32_16x16x32_bf16(fa0.v, bfr[0][0], zero, 0, 0, 0);
            c0_       = __builtin_amdgcn_mfma_f32_16x16x32_bf16(fa1.v, bfr[0][1], c0_, 0, 0, 0);
            f32x4 c1_ = __builtin_amdgcn_mfma_f32_16x16x32_bf16(fa0.v, bfr[1][0], zero, 0, 0, 0);
            c1_       = __builtin_amdgcn_mfma_f32_16x16x32_bf16(fa1.v, bfr[1][1], c1_, 0, 0, 0);

            f32x4 sq = *(const f32x4*)&sqw[m][16 * w + 4 * q];
            const float pe0[4] = { h2f(penr0[m].x), h2f(penr0[m].y),
                                   h2f(penr0[m].z), h2f(penr0[m].w) };
            const float pe1[4] = { h2f(penr1[m].x), h2f(penr1[m].y),
                                   h2f(penr1[m].z), h2f(penr1[m].w) };
#pragma unroll
            for (int r = 0; r < 4; ++r) {
                float t0v = fmaf(-2.f, c0_[r], sq[r] + ssk0);
                wd0[r] = fmaf(pe0[r], t0v, wd0[r]);
                float t1v = fmaf(-2.f, c1_[r], sq[r] + ssk1);
                wd1[r] = fmaf(pe1[r], t1v, wd1[r]);
            }
        }

        // ---- min over 4 rows -> across quads -> atomicMin per (b,k) ----
#pragma unroll
        for (int t = 0; t < 2; ++t) {
            float lmin = __int_as_float(0x7F800000);
            const f32x4& wdv = t ? wd1 : wd0;
#pragma unroll
            for (int r = 0; r < 4; ++r) {
                if (nrow + r < N_) lmin = fminf(lmin, wdv[r]);
            }
            lmin = fminf(lmin, __shfl_xor(lmin, 16));
            lmin = fminf(lmin, __shfl_xor(lmin, 32));
            if (q == 0) {
                atomicMin(out + (size_t)b * K_ + 16 * t + rl,
                          __float_as_uint(fmaxf(lmin, 0.f)));
            }
        }
        __syncthreads();   // protect xbuf4/sqw restage for next b
    }
}

extern "C" void kernel_launch(void* const* d_in, const int* in_sizes, int n_in,
                              void* d_out, int out_size, void* d_ws, size_t ws_size,
                              hipStream_t stream) {
    const float* x    = (const float*)d_in[0];   // (B, M, T)
    const float* shp  = (const float*)d_in[1];   // (K, L)
    const float* pmap = (const float*)d_in[2];   // (K, M, N)
    unsigned* out = (unsigned*)d_out;            // (B, K) float bits
    unsigned short* pen_h = (unsigned short*)d_ws;   // (M, NQP, K, 4) fp16, 2 MB
    float* ss_ws = (float*)(pen_h + (size_t)M_ * NQP * K_ * 4);

    const int work = M_ * NQP * K_;              // 262144 threads
    pen_init_kernel<<<dim3(work / 256), dim3(256), 0, stream>>>(
        pmap, shp, pen_h, ss_ws, out);

    dim3 grid((N_ + TN - 1) / TN, B_ / NBB);     // 32 x 16 = 512 blocks, 2/CU
    shapelet_mfma_kernel<<<grid, dim3(NTH), 0, stream>>>(x, shp, pen_h, ss_ws, out);
}

// Round 15
// 102.140 us; speedup vs baseline: 1.2991x; 1.2991x over previous
//
#include <hip/hip_runtime.h>
#include <hip/hip_bf16.h>

// B=64, M=16, T=2048, L=64, K=32, N=1985
#define B_ 64
#define M_ 16
#define T_ 2048
#define L_ 64
#define K_ 32
#define N_ (T_ - L_ + 1)   // 1985
#define NQP 512            // padded n-quad rows per m in pen_t (no guards)
#define XBS 2112           // xbf row stride elems (2048 + 64 zero pad -> no guards)
#define SQS 2048           // sqwin row stride
#define TN 64              // n-positions per block (4 waves x 16-n subtiles)
#define NTH 256
#define XRW 80             // per-(wave,m) plane row elems; need cols<=75.
                           // 40 dw == 8 (mod 32) -> planes at bank offs {0,8,16,24}:
                           // uniform 4 touches/bank per wave read = LDS floor.
#define SQWP 20            // private sqw row stride (16 + 4)

typedef __attribute__((ext_vector_type(8))) short bf16x8;
typedef __attribute__((ext_vector_type(4))) float f32x4;

__device__ __forceinline__ unsigned short f2bf(float f) {
    __hip_bfloat16 h = __float2bfloat16(f);
    return __builtin_bit_cast(unsigned short, h);
}
// low 32 of ((hi:lo) >> 16) -> v_alignbit_b32
__device__ __forceinline__ unsigned fun16(unsigned lo, unsigned hi) {
    return (unsigned)(((((unsigned long long)hi) << 32) | lo) >> 16);
}

// pen_t[m][nq][k][r] = elu(-pmap[k][m][clamp(4nq+r)]) + 2 (fp32, quad-contiguous);
// ss[k] = sum_l s^2; out[] = +inf.
__global__ void pen_init_kernel(const float* __restrict__ pmap,
                                const float* __restrict__ shp,
                                float* __restrict__ pen_t,
                                float* __restrict__ ss_ws,
                                unsigned* __restrict__ out) {
    const int gid = blockIdx.x * 256 + threadIdx.x;   // 0 .. M*NQP*K-1 (262144)
    if (gid < B_ * K_) out[gid] = 0x7F800000u;  // +inf
    if (gid < K_) {
        float s = 0.f;
        for (int l = 0; l < L_; ++l) { float v = shp[gid * L_ + l]; s = fmaf(v, v, s); }
        ss_ws[gid] = s;
    }
    if (gid < M_ * NQP * K_) {
        const int m  = gid >> 14;
        const int rem = gid & 16383;
        const int nq = rem >> 5;
        const int k  = rem & 31;
        const float* src = pmap + ((size_t)k * M_ + m) * N_;
        float4 r; float* pr = (float*)&r;
#pragma unroll
        for (int i = 0; i < 4; ++i) {
            int n = 4 * nq + i; if (n >= N_) n = N_ - 1;   // clamp: masked at min
            const float p = src[n];
            pr[i] = (p < 0.f) ? (2.f - p) : (__expf(-p) + 1.f);
        }
        *(float4*)(pen_t + (size_t)gid * 4) = r;
    }
}

// Per (b,m) row: xbf = bf16(x) padded with zeros to XBS; sqwin = fp32 sliding
// sum of squares over 64-windows, full 2048 entries (values >= N finite garbage,
// masked at the min).
__global__ __launch_bounds__(256)
void xprep_kernel(const float* __restrict__ x,
                  unsigned short* __restrict__ xbf,
                  float* __restrict__ sqwin) {
    __shared__ __align__(16) float xrow[T_ + 64];
    const int r = blockIdx.x;            // b*16 + m
    const int tid = threadIdx.x;
    const float* src = x + (size_t)r * T_;
#pragma unroll
    for (int i = 0; i < 2; ++i) {
        const int i4 = 4 * (tid + 256 * i);
        float4 v = *(const float4*)(src + i4);
        *(float4*)&xrow[i4] = v;
        ushort4 sv = { f2bf(v.x), f2bf(v.y), f2bf(v.z), f2bf(v.w) };
        *(ushort4*)(xbf + (size_t)r * XBS + i4) = sv;
    }
    if (tid < 16) *(float4*)&xrow[T_ + 4 * tid] = make_float4(0.f, 0.f, 0.f, 0.f);
    if (tid < 16) {
        ushort4 z = { 0, 0, 0, 0 };
        *(ushort4*)(xbf + (size_t)r * XBS + T_ + 4 * tid) = z;
    }
    __syncthreads();
    const int n0t = 8 * tid;             // 8 windows per thread, covers 0..2047
    float s = 0.f;
#pragma unroll
    for (int qd = 0; qd < 16; ++qd) {
        float4 v = *(const float4*)&xrow[n0t + 4 * qd];
        s = fmaf(v.x, v.x, s); s = fmaf(v.y, v.y, s);
        s = fmaf(v.z, v.z, s); s = fmaf(v.w, v.w, s);
    }
    float* dst = sqwin + (size_t)r * SQS + n0t;
    dst[0] = s;
#pragma unroll
    for (int d = 1; d < 8; ++d) {
        float a = xrow[n0t + d + L_ - 1], rm = xrow[n0t + d - 1];
        s += a * a - rm * rm;
        dst[d] = s;
    }
}

// BARRIER-FREE main kernel: each wave stages its own LDS region and computes.
__global__ __launch_bounds__(NTH, 3)
void shapelet_mfma_kernel(const unsigned short* __restrict__ xbf,
                          const float* __restrict__ sqwin,
                          const float* __restrict__ shp,
                          const float* __restrict__ pen_t,
                          const float* __restrict__ ss_ws,
                          unsigned* __restrict__ out) {
    // LDS: 40960 + 5120 = 46080 B -> 3 blocks/CU (12 independent waves/CU)
    __shared__ __align__(16) unsigned short xw[4][M_][4][XRW];  // wave-private planes
    __shared__ __align__(16) float sqw[4][M_][SQWP];            // wave-private sqw

    const int tid = threadIdx.x;
    const int lane = tid & 63;
    const int w  = tid >> 6;            // wave id -> private region + n-subtile
    const int rl = lane & 15;           // A-row (n in subtile) / B-col (k in tile)
    const int q  = lane >> 4;           // quad
    const int n0 = blockIdx.x * TN;
    const int b  = blockIdx.y;
    const int nb = n0 + 16 * w;         // wave's subtile base (<= 2032)

    // ---- stage wave-private shifted planes from xbf (bf16; 3 alignbits/group) ----
    for (int i = lane; i < M_ * 19; i += 64) {
        const int m = i / 19, j4 = (i - m * 19) * 4;    // j4 in {0..72}
        const unsigned short* s8 = xbf + ((size_t)(b * M_ + m)) * XBS + nb + j4;
        uint2 a = *(const uint2*)s8;          // elems j4..j4+3
        uint2 c = *(const uint2*)(s8 + 4);    // elems j4+4..j4+7  (max 2111 < XBS*rows)
        const unsigned u0 = a.x, u1 = a.y, u2 = c.x, u3 = c.y;
        const unsigned a01 = fun16(u0, u1);   // (e2<<16)|e1
        const unsigned a12 = fun16(u1, u2);   // (e4<<16)|e3
        const unsigned a23 = fun16(u2, u3);   // (e6<<16)|e5
        uint2 p;
        p.x = u0;  p.y = u1;  *(uint2*)&xw[w][m][0][j4] = p;   // e0..e3
        p.x = a01; p.y = a12; *(uint2*)&xw[w][m][1][j4] = p;   // e1..e4
        p.x = u1;  p.y = u2;  *(uint2*)&xw[w][m][2][j4] = p;   // e2..e5
        p.x = a12; p.y = a23; *(uint2*)&xw[w][m][3][j4] = p;   // e3..e6
    }
    // ---- stage wave-private sqw: ONE float4 load per lane ----
    {
        const int m = lane >> 2, n4 = (lane & 3) * 4;
        float4 v = *(const float4*)(sqwin + ((size_t)(b * M_ + m)) * SQS + nb + n4);
        *(float4*)&sqw[w][m][n4] = v;
    }
    // ---- B-frags straight from global shp (no LDS, no barrier) ----
    bf16x8 bfr[2][2];
#pragma unroll
    for (int t = 0; t < 2; ++t)
#pragma unroll
        for (int h = 0; h < 2; ++h) {
            const float* sp_ = shp + (16 * t + rl) * L_ + 8 * q + 32 * h;
            float4 v0 = *(const float4*)sp_;
            float4 v1 = *(const float4*)(sp_ + 4);
            union { unsigned short us[8]; bf16x8 v; } cv;
            cv.us[0] = f2bf(v0.x); cv.us[1] = f2bf(v0.y);
            cv.us[2] = f2bf(v0.z); cv.us[3] = f2bf(v0.w);
            cv.us[4] = f2bf(v1.x); cv.us[5] = f2bf(v1.y);
            cv.us[6] = f2bf(v1.z); cv.us[7] = f2bf(v1.w);
            bfr[t][h] = cv.v;
        }

    const float ssk0 = ss_ws[rl], ssk1 = ss_ws[16 + rl];
    const int sp = rl & 3;
    const int e0s = 8 * q + (rl & ~3);   // 4-aligned elem base within subtile (<=36)
    const int eqi = e0s >> 2;            // uint2 index (<=9; +9 = 18 < 20)
    const int nrow = nb + 4 * q;

    const int nq_l = (n0 >> 2) + 4 * w + q;
    const float* pt0 = pen_t + (((size_t)nq_l) * K_ + rl) * 4;

    f32x4 wd0 = (f32x4)0.f, wd1 = (f32x4)0.f;
    const f32x4 zero = (f32x4)0.f;

#pragma unroll 2
    for (int m = 0; m < M_; ++m) {
        float4 p0 = *(const float4*)(pt0 + (size_t)m * (NQP * K_ * 4));
        float4 p1 = *(const float4*)(pt0 + (size_t)m * (NQP * K_ * 4) + 64);

        const uint2* prow = (const uint2*)&xw[w][m][sp][0];
        uint2 lo0 = prow[eqi],     hi0 = prow[eqi + 1];      // frag h=0
        uint2 lo1 = prow[eqi + 8], hi1 = prow[eqi + 9];      // frag h=1 (+32 elems)
        union { uint2 u2[2]; bf16x8 v; } fa0, fa1;
        fa0.u2[0] = lo0; fa0.u2[1] = hi0;
        fa1.u2[0] = lo1; fa1.u2[1] = hi1;

        f32x4 c0_ = __builtin_amdgcn_mfma_f32_16x16x32_bf16(fa0.v, bfr[0][0], zero, 0, 0, 0);
        c0_       = __builtin_amdgcn_mfma_f32_16x16x32_bf16(fa1.v, bfr[0][1], c0_, 0, 0, 0);
        f32x4 c1_ = __builtin_amdgcn_mfma_f32_16x16x32_bf16(fa0.v, bfr[1][0], zero, 0, 0, 0);
        c1_       = __builtin_amdgcn_mfma_f32_16x16x32_bf16(fa1.v, bfr[1][1], c1_, 0, 0, 0);

        f32x4 sq = *(const f32x4*)&sqw[w][m][4 * q];
        const float pe0[4] = { p0.x, p0.y, p0.z, p0.w };
        const float pe1[4] = { p1.x, p1.y, p1.z, p1.w };
#pragma unroll
        for (int r = 0; r < 4; ++r) {
            float t0v = fmaf(-2.f, c0_[r], sq[r] + ssk0);
            wd0[r] = fmaf(pe0[r], t0v, wd0[r]);
            float t1v = fmaf(-2.f, c1_[r], sq[r] + ssk1);
            wd1[r] = fmaf(pe1[r], t1v, wd1[r]);
        }
    }

    // ---- min over 4 rows -> across quads -> atomicMin per (b,k) ----
#pragma unroll
    for (int t = 0; t < 2; ++t) {
        float lmin = __int_as_float(0x7F800000);
        const f32x4& wdv = t ? wd1 : wd0;
#pragma unroll
        for (int r = 0; r < 4; ++r) {
            if (nrow + r < N_) lmin = fminf(lmin, wdv[r]);
        }
        lmin = fminf(lmin, __shfl_xor(lmin, 16));
        lmin = fminf(lmin, __shfl_xor(lmin, 32));
        if (q == 0) {
            atomicMin(out + (size_t)b * K_ + 16 * t + rl,
                      __float_as_uint(fmaxf(lmin, 0.f)));
        }
    }
}

extern "C" void kernel_launch(void* const* d_in, const int* in_sizes, int n_in,
                              void* d_out, int out_size, void* d_ws, size_t ws_size,
                              hipStream_t stream) {
    const float* x    = (const float*)d_in[0];   // (B, M, T)
    const float* shp  = (const float*)d_in[1];   // (K, L)
    const float* pmap = (const float*)d_in[2];   // (K, M, N)
    unsigned* out = (unsigned*)d_out;            // (B, K) float bits

    // ws layout (all 16B-aligned): pen_t 4MB | ss 128B.. | xbf 4.125MB | sqwin 8MB
    float* pen_t = (float*)d_ws;                               // M*NQP*K*4 floats
    float* ss_ws = pen_t + (size_t)M_ * NQP * K_ * 4;          // 32 floats (+pad)
    unsigned short* xbf = (unsigned short*)(ss_ws + 64);       // B*M*XBS ushorts
    float* sqwin = (float*)(xbf + (size_t)B_ * M_ * XBS);      // B*M*SQS floats

    pen_init_kernel<<<dim3(M_ * NQP * K_ / 256), dim3(256), 0, stream>>>(
        pmap, shp, pen_t, ss_ws, out);
    xprep_kernel<<<dim3(B_ * M_), dim3(256), 0, stream>>>(x, xbf, sqwin);

    dim3 grid((N_ + TN - 1) / TN, B_);           // 32 x 64 = 2048 blocks, 3/CU
    shapelet_mfma_kernel<<<grid, dim3(NTH), 0, stream>>>(
        xbf, sqwin, shp, pen_t, ss_ws, out);
}